// Round 8
// baseline (131.306 us; speedup 1.0000x reference)
//
#include <hip/hip_runtime.h>
#include <stdint.h>

typedef unsigned long long u64;
typedef unsigned int u32;
typedef float vfloat4 __attribute__((ext_vector_type(4)));

#define VOX     32768      // 32*32*32
#define KCAP    512        // candidate cap (matches reference K; npos <= NPTS=400)
#define MAXEV   100        // max_events
#define NBRCAP  26         // geometric max conflicts per point (26-neighborhood)
#define K1_BPF  8          // stage blocks per frame
#define K1_THREADS 256
#define K2_THREADS 512
#define SEGCAP  512        // per-(frame,chunk) candidate segment capacity

// dist < 2.0 on integer coords  <=>  Chebyshev distance <= 1 (3x3x3 cube)
// Priority key: (float_bits(val) << 32) | ~vox  — vals > 0 so float bits are
// monotone; higher val => bigger key; tie => lower vox => bigger key.
// hp(i over t) <=> key[i] > key[t]. Keys unique (voxels unique).
//
// ws layout (no zeroing needed — every word rewritten each launch):
//   gcnt int[256*8]  @ 0        : per-(frame,chunk) candidate count
//   gnz  int[256*8]  @ 65536    : per-(frame,chunk) any-nonzero flag
//   grec u64[256*8*SEGCAP] @ 131072 : per-(frame,chunk) key segments (8 MB)

// ---------------------------------------------------------------------------
// Kernel 1: pure streaming, zero inter-block communication. Zero-fill output,
// read energy, collect positives in LDS, flush to a PRIVATE global segment.
// All streaming accesses nontemporal: 100 MB of single-touch traffic.
// ---------------------------------------------------------------------------
__global__ __launch_bounds__(K1_THREADS) void stage_kernel(
    const float* __restrict__ x, float* __restrict__ out,
    int* __restrict__ gcnt, int* __restrict__ gnz, u64* __restrict__ grec)
{
    const int bid = blockIdx.x;
    const int f   = bid / K1_BPF;
    const int c   = bid % K1_BPF;
    const int tid = threadIdx.x;

    __shared__ u64 sbuf[SEGCAP];    // per-block candidate keys (4 KB)
    __shared__ int s_cnt, s_nz;

    if (tid == 0) { s_cnt = 0; s_nz = 0; }
    __syncthreads();

    // zero-fill this block's slice of the [2,V] output (8 float4 / thread, NT)
    {
        vfloat4* o4 = (vfloat4*)(out + (size_t)f * 2 * VOX) + c * (2 * VOX / K1_BPF / 4);
        const vfloat4 z = {0.f, 0.f, 0.f, 0.f};
        #pragma unroll
        for (int h = 0; h < (2 * VOX / K1_BPF / 4) / K1_THREADS; ++h)
            __builtin_nontemporal_store(z, &o4[tid + h * K1_THREADS]);
    }

    // read this block's slice of the energy channel (4 float4 / thread, NT)
    const vfloat4* e4 = (const vfloat4*)(x + (size_t)f * 2 * VOX) + c * (VOX / K1_BPF / 4);
    bool anynz = false;
    #pragma unroll
    for (int h = 0; h < (VOX / K1_BPF / 4) / K1_THREADS; ++h) {
        int li = tid + h * K1_THREADS;                    // local float4 index
        vfloat4 v = __builtin_nontemporal_load(&e4[li]);
        int vbase = c * (VOX / K1_BPF) + li * 4;          // voxel of component 0
        #pragma unroll
        for (int cc = 0; cc < 4; ++cc) {
            float val = v[cc];
            anynz |= (val != 0.f);
            if (val > 0.f) {                              // rare (~6/thread)
                int slot = atomicAdd(&s_cnt, 1);          // LDS atomic: cheap
                if (slot < SEGCAP) {
                    int vox = vbase + cc;
                    sbuf[slot] = ((u64)__float_as_uint(val) << 32) | (u64)(~(u32)vox);
                }
            }
        }
    }
    if (anynz) s_nz = 1;                                  // benign race
    __syncthreads();

    const int cnt = min(s_cnt, SEGCAP);
    // flush to private segment + unconditional count/flag stores (no atomics)
    for (int i = tid; i < cnt; i += K1_THREADS)
        grec[((size_t)f * K1_BPF + c) * SEGCAP + i] = sbuf[i];
    if (tid == 0) {
        gcnt[f * K1_BPF + c] = cnt;
        gnz [f * K1_BPF + c] = s_nz;
    }
}

// ---------------------------------------------------------------------------
// Kernel 2: per-frame NMS on the 8 gathered segments + direct scatter of
// survivors onto the pre-zeroed output. 1 block/frame, LDS-resident.
// ---------------------------------------------------------------------------
__global__ __launch_bounds__(K2_THREADS) void nms_scatter_kernel(
    const float* __restrict__ x, float* __restrict__ out,
    const int* __restrict__ gcnt, const int* __restrict__ gnz,
    const u64* __restrict__ grec)
{
    const int f    = blockIdx.x;
    const int tid  = threadIdx.x;
    const int wave = tid >> 6;
    const int lane = tid & 63;

    __shared__ unsigned short smap[VOX];            // voxel -> slot (0xFFFF none), 64 KB
    __shared__ u64   skey[KCAP];
    __shared__ short srank[KCAP];
    __shared__ unsigned char status[KCAP];          // 0 undecided, 1 kept, 2 suppressed
    __shared__ unsigned short pnbr[KCAP * NBRCAP];  // higher-priority conflicts
    __shared__ int s_off[K1_BPF + 1];
    __shared__ int s_nz, s_nkept, s_undec;

    // gather segment counts -> offsets (thread 0, 8 iterations: trivial)
    if (tid == 0) {
        int acc = 0, nz = 0;
        #pragma unroll
        for (int c = 0; c < K1_BPF; ++c) {
            s_off[c] = acc;
            acc += gcnt[f * K1_BPF + c];
            nz  |= gnz [f * K1_BPF + c];
        }
        s_off[K1_BPF] = acc;
        s_nz = nz;
        s_nkept = 0;
    }
    {   // init voxel map (concurrent with thread-0 scan)
        u32* m32 = (u32*)smap;
        #pragma unroll
        for (int h = 0; h < VOX / 2 / K2_THREADS; ++h)
            m32[tid + h * K2_THREADS] = 0xFFFFFFFFu;
    }
    __syncthreads();

    const int n = min(s_off[K1_BPF], KCAP);

    if (s_nz == 0) {
        // empty frame: pass input through (overwrites the zero-fill)
        const vfloat4* x4 = (const vfloat4*)(x + (size_t)f * 2 * VOX);
        vfloat4*       o4 = (vfloat4*)(out + (size_t)f * 2 * VOX);
        for (int i = tid; i < 2 * VOX / 4; i += K2_THREADS)
            __builtin_nontemporal_store(__builtin_nontemporal_load(&x4[i]), &o4[i]);
        return;
    }

    // wave w gathers segment w into the packed key array + voxel map
    {
        const int cnt  = s_off[wave + 1] - s_off[wave];
        const int base = s_off[wave];
        const u64* seg = grec + ((size_t)f * K1_BPF + wave) * SEGCAP;
        for (int i = lane; i < cnt; i += 64) {
            int o = base + i;
            if (o < KCAP) {
                u64 k = seg[i];
                skey[o] = k;
                smap[(int)(~(u32)k) & (VOX - 1)] = (unsigned short)o;
            }
        }
    }
    __syncthreads();

    // rank (pure broadcast loop, pipelines) + neighbors via 26 map probes
    int pcnt = 0;
    if (tid < n) {
        const u64 kt = skey[tid];
        int rank = 0;
        #pragma unroll 8
        for (int i = 0; i < n; ++i)
            rank += (skey[i] > kt);
        srank[tid] = (short)rank;

        const int vox = (int)(~(u32)kt) & (VOX - 1);
        const int zt = vox >> 10, yt = (vox >> 5) & 31, xt = vox & 31;
        #pragma unroll
        for (int dz = -1; dz <= 1; ++dz) {
            int z = zt + dz; if ((unsigned)z >= 32) continue;
            #pragma unroll
            for (int dy = -1; dy <= 1; ++dy) {
                int yy = yt + dy; if ((unsigned)yy >= 32) continue;
                #pragma unroll
                for (int dx = -1; dx <= 1; ++dx) {
                    int xx = xt + dx; if ((unsigned)xx >= 32) continue;
                    int nv = (z << 10) | (yy << 5) | xx;
                    if (nv == vox) continue;
                    unsigned short m = smap[nv];
                    if (m != 0xFFFFu && skey[m] > kt)
                        pnbr[tid * NBRCAP + pcnt++] = m;
                }
            }
        }
        status[tid] = (pcnt == 0) ? (unsigned char)1 : (unsigned char)0;
    }
    __syncthreads();

    // parallel greedy resolution (monotone label propagation; converges in
    // <= n rounds since the highest-priority undecided point always resolves)
    for (int round = 0; round < KCAP; ++round) {
        if (tid == 0) s_undec = 0;
        __syncthreads();
        if (tid < n && status[tid] == 0) {
            bool anyKept = false, anyUndec = false;
            for (int p = 0; p < pcnt; ++p) {
                unsigned char s = status[pnbr[tid * NBRCAP + p]];
                anyKept  |= (s == 1);
                anyUndec |= (s == 0);
            }
            if (anyKept)        status[tid] = 2;
            else if (!anyUndec) status[tid] = 1;
            else                s_undec = 1;        // benign race: all write 1
        }
        __syncthreads();
        if (s_undec == 0) break;
    }

    // count kept, apply rank truncation, scatter survivors to output
    if (tid < n && status[tid] == 1) atomicAdd(&s_nkept, 1);
    __syncthreads();
    const int nkept = s_nkept;
    if (tid < n && status[tid] == 1 &&
        !(nkept > MAXEV && srank[tid] >= MAXEV)) {
        u64 k = skey[tid];
        int   vox = (int)(~(u32)k) & (VOX - 1);
        float val = __uint_as_float((u32)(k >> 32));
        float* of = out + (size_t)f * 2 * VOX;
        of[vox]       = val;                                   // exact energy copy
        of[VOX + vox] = x[(size_t)f * 2 * VOX + VOX + vox];    // exact magnitude copy
    }
}

extern "C" void kernel_launch(void* const* d_in, const int* in_sizes, int n_in,
                              void* d_out, int out_size, void* d_ws, size_t ws_size,
                              hipStream_t stream) {
    const float* x = (const float*)d_in[0];
    float* out = (float*)d_out;
    int frames = in_sizes[0] / (2 * VOX);   // B*T = 256

    int* gcnt = (int*)d_ws;                             // [256*8]
    int* gnz  = (int*)((char*)d_ws + 65536);            // [256*8]
    u64* grec = (u64*)((char*)d_ws + 131072);           // [256*8*SEGCAP]

    stage_kernel<<<frames * K1_BPF, K1_THREADS, 0, stream>>>(x, out, gcnt, gnz, grec);
    nms_scatter_kernel<<<frames, K2_THREADS, 0, stream>>>(x, out, gcnt, gnz, grec);
}

// Round 9
// 121.032 us; speedup vs baseline: 1.0849x; 1.0849x over previous
//
#include <hip/hip_runtime.h>
#include <stdint.h>

typedef unsigned long long u64;
typedef unsigned int u32;

#define VOX     32768      // 32*32*32
#define KCAP    512        // candidate cap (matches reference K; npos <= NPTS=400)
#define MAXEV   100        // max_events
#define NBRCAP  26         // geometric max conflicts per point (26-neighborhood)
#define K1_BPF  8          // stage blocks per frame
#define K1_THREADS 256
#define K2_THREADS 512
#define SEGCAP  512        // per-(frame,chunk) candidate segment capacity

// dist < 2.0 on integer coords  <=>  Chebyshev distance <= 1 (3x3x3 cube)
// Priority key: (float_bits(val) << 32) | ~vox  — vals > 0 so float bits are
// monotone; higher val => bigger key; tie => lower vox => bigger key.
// hp(i over t) <=> key[i] > key[t]. Keys unique (voxels unique).
//
// NOTE (R8 post-mortem): nontemporal loads/stores REGRESSED +9 us here —
// the harness's per-iteration input restore leaves x hot in L2/L3, and NT
// loads bypass that. Keep regular cached accesses.
//
// ws layout (no zeroing needed — every word rewritten each launch):
//   gcnt int[256*8]  @ 0        : per-(frame,chunk) candidate count
//   gnz  int[256*8]  @ 65536    : per-(frame,chunk) any-nonzero flag
//   grec u64[256*8*SEGCAP] @ 131072 : per-(frame,chunk) key segments (8 MB)

// ---------------------------------------------------------------------------
// Kernel 1: pure streaming, zero inter-block communication. Energy loads are
// issued FIRST so their latency overlaps the zero-fill store stream; then
// collect positives in LDS and flush to a PRIVATE global segment.
// ---------------------------------------------------------------------------
__global__ __launch_bounds__(K1_THREADS) void stage_kernel(
    const float* __restrict__ x, float* __restrict__ out,
    int* __restrict__ gcnt, int* __restrict__ gnz, u64* __restrict__ grec)
{
    const int bid = blockIdx.x;
    const int f   = bid / K1_BPF;
    const int c   = bid % K1_BPF;
    const int tid = threadIdx.x;

    __shared__ u64 sbuf[SEGCAP];    // per-block candidate keys (4 KB)
    __shared__ int s_cnt, s_nz;

    if (tid == 0) { s_cnt = 0; s_nz = 0; }
    __syncthreads();

    // issue all energy loads first (4 float4 / thread)
    const float4* e4 = (const float4*)(x + (size_t)f * 2 * VOX) + c * (VOX / K1_BPF / 4);
    float4 v[(VOX / K1_BPF / 4) / K1_THREADS];
    #pragma unroll
    for (int h = 0; h < (VOX / K1_BPF / 4) / K1_THREADS; ++h)
        v[h] = e4[tid + h * K1_THREADS];

    // zero-fill this block's slice of the [2,V] output (8 float4 / thread)
    // while the loads are in flight
    {
        float4* o4 = (float4*)(out + (size_t)f * 2 * VOX) + c * (2 * VOX / K1_BPF / 4);
        const float4 z = make_float4(0.f, 0.f, 0.f, 0.f);
        #pragma unroll
        for (int h = 0; h < (2 * VOX / K1_BPF / 4) / K1_THREADS; ++h)
            o4[tid + h * K1_THREADS] = z;
    }

    // scan the loaded values for positives
    bool anynz = false;
    #pragma unroll
    for (int h = 0; h < (VOX / K1_BPF / 4) / K1_THREADS; ++h) {
        int li = tid + h * K1_THREADS;                    // local float4 index
        int vbase = c * (VOX / K1_BPF) + li * 4;          // voxel of component 0
        float vv[4] = {v[h].x, v[h].y, v[h].z, v[h].w};
        #pragma unroll
        for (int cc = 0; cc < 4; ++cc) {
            float val = vv[cc];
            anynz |= (val != 0.f);
            if (val > 0.f) {                              // rare (~6/thread)
                int slot = atomicAdd(&s_cnt, 1);          // LDS atomic: cheap
                if (slot < SEGCAP) {
                    int vox = vbase + cc;
                    sbuf[slot] = ((u64)__float_as_uint(val) << 32) | (u64)(~(u32)vox);
                }
            }
        }
    }
    if (anynz) s_nz = 1;                                  // benign race
    __syncthreads();

    const int cnt = min(s_cnt, SEGCAP);
    // flush to private segment + unconditional count/flag stores (no atomics)
    for (int i = tid; i < cnt; i += K1_THREADS)
        grec[((size_t)f * K1_BPF + c) * SEGCAP + i] = sbuf[i];
    if (tid == 0) {
        gcnt[f * K1_BPF + c] = cnt;
        gnz [f * K1_BPF + c] = s_nz;
    }
}

// ---------------------------------------------------------------------------
// Kernel 2: per-frame NMS on the 8 gathered segments + direct scatter of
// survivors onto the pre-zeroed output. 1 block/frame, LDS-resident.
// ---------------------------------------------------------------------------
__global__ __launch_bounds__(K2_THREADS) void nms_scatter_kernel(
    const float* __restrict__ x, float* __restrict__ out,
    const int* __restrict__ gcnt, const int* __restrict__ gnz,
    const u64* __restrict__ grec)
{
    const int f    = blockIdx.x;
    const int tid  = threadIdx.x;
    const int wave = tid >> 6;
    const int lane = tid & 63;

    __shared__ unsigned short smap[VOX];            // voxel -> slot (0xFFFF none), 64 KB
    __shared__ u64   skey[KCAP];
    __shared__ short srank[KCAP];
    __shared__ unsigned char status[KCAP];          // 0 undecided, 1 kept, 2 suppressed
    __shared__ unsigned short pnbr[KCAP * NBRCAP];  // higher-priority conflicts
    __shared__ int s_off[K1_BPF + 1];
    __shared__ int s_nz, s_nkept, s_undec;

    // gather segment counts -> offsets (thread 0, 8 iterations: trivial)
    if (tid == 0) {
        int acc = 0, nz = 0;
        #pragma unroll
        for (int c = 0; c < K1_BPF; ++c) {
            s_off[c] = acc;
            acc += gcnt[f * K1_BPF + c];
            nz  |= gnz [f * K1_BPF + c];
        }
        s_off[K1_BPF] = acc;
        s_nz = nz;
        s_nkept = 0;
    }
    {   // init voxel map (concurrent with thread-0 scan)
        u32* m32 = (u32*)smap;
        #pragma unroll
        for (int h = 0; h < VOX / 2 / K2_THREADS; ++h)
            m32[tid + h * K2_THREADS] = 0xFFFFFFFFu;
    }
    __syncthreads();

    const int n = min(s_off[K1_BPF], KCAP);

    if (s_nz == 0) {
        // empty frame: pass input through (overwrites the zero-fill)
        const float4* x4 = (const float4*)(x + (size_t)f * 2 * VOX);
        float4*       o4 = (float4*)(out + (size_t)f * 2 * VOX);
        for (int i = tid; i < 2 * VOX / 4; i += K2_THREADS) o4[i] = x4[i];
        return;
    }

    // wave w gathers segment w into the packed key array + voxel map
    {
        const int cnt  = s_off[wave + 1] - s_off[wave];
        const int base = s_off[wave];
        const u64* seg = grec + ((size_t)f * K1_BPF + wave) * SEGCAP;
        for (int i = lane; i < cnt; i += 64) {
            int o = base + i;
            if (o < KCAP) {
                u64 k = seg[i];
                skey[o] = k;
                smap[(int)(~(u32)k) & (VOX - 1)] = (unsigned short)o;
            }
        }
    }
    __syncthreads();

    // rank (pure broadcast loop, pipelines) + neighbors via 26 map probes
    int pcnt = 0;
    if (tid < n) {
        const u64 kt = skey[tid];
        int rank = 0;
        #pragma unroll 8
        for (int i = 0; i < n; ++i)
            rank += (skey[i] > kt);
        srank[tid] = (short)rank;

        const int vox = (int)(~(u32)kt) & (VOX - 1);
        const int zt = vox >> 10, yt = (vox >> 5) & 31, xt = vox & 31;
        #pragma unroll
        for (int dz = -1; dz <= 1; ++dz) {
            int z = zt + dz; if ((unsigned)z >= 32) continue;
            #pragma unroll
            for (int dy = -1; dy <= 1; ++dy) {
                int yy = yt + dy; if ((unsigned)yy >= 32) continue;
                #pragma unroll
                for (int dx = -1; dx <= 1; ++dx) {
                    int xx = xt + dx; if ((unsigned)xx >= 32) continue;
                    int nv = (z << 10) | (yy << 5) | xx;
                    if (nv == vox) continue;
                    unsigned short m = smap[nv];
                    if (m != 0xFFFFu && skey[m] > kt)
                        pnbr[tid * NBRCAP + pcnt++] = m;
                }
            }
        }
        status[tid] = (pcnt == 0) ? (unsigned char)1 : (unsigned char)0;
    }
    __syncthreads();

    // parallel greedy resolution (monotone label propagation; converges in
    // <= n rounds since the highest-priority undecided point always resolves)
    for (int round = 0; round < KCAP; ++round) {
        if (tid == 0) s_undec = 0;
        __syncthreads();
        if (tid < n && status[tid] == 0) {
            bool anyKept = false, anyUndec = false;
            for (int p = 0; p < pcnt; ++p) {
                unsigned char s = status[pnbr[tid * NBRCAP + p]];
                anyKept  |= (s == 1);
                anyUndec |= (s == 0);
            }
            if (anyKept)        status[tid] = 2;
            else if (!anyUndec) status[tid] = 1;
            else                s_undec = 1;        // benign race: all write 1
        }
        __syncthreads();
        if (s_undec == 0) break;
    }

    // count kept, apply rank truncation, scatter survivors to output
    if (tid < n && status[tid] == 1) atomicAdd(&s_nkept, 1);
    __syncthreads();
    const int nkept = s_nkept;
    if (tid < n && status[tid] == 1 &&
        !(nkept > MAXEV && srank[tid] >= MAXEV)) {
        u64 k = skey[tid];
        int   vox = (int)(~(u32)k) & (VOX - 1);
        float val = __uint_as_float((u32)(k >> 32));
        float* of = out + (size_t)f * 2 * VOX;
        of[vox]       = val;                                   // exact energy copy
        of[VOX + vox] = x[(size_t)f * 2 * VOX + VOX + vox];    // exact magnitude copy
    }
}

extern "C" void kernel_launch(void* const* d_in, const int* in_sizes, int n_in,
                              void* d_out, int out_size, void* d_ws, size_t ws_size,
                              hipStream_t stream) {
    const float* x = (const float*)d_in[0];
    float* out = (float*)d_out;
    int frames = in_sizes[0] / (2 * VOX);   // B*T = 256

    int* gcnt = (int*)d_ws;                             // [256*8]
    int* gnz  = (int*)((char*)d_ws + 65536);            // [256*8]
    u64* grec = (u64*)((char*)d_ws + 131072);           // [256*8*SEGCAP]

    stage_kernel<<<frames * K1_BPF, K1_THREADS, 0, stream>>>(x, out, gcnt, gnz, grec);
    nms_scatter_kernel<<<frames, K2_THREADS, 0, stream>>>(x, out, gcnt, gnz, grec);
}